// Round 7
// baseline (245.020 us; speedup 1.0000x reference)
//
#include <hip/hip_runtime.h>
#include <stdint.h>

// occupancy_generation (DeepMapping2D):
//   out[b, j] = 1.0 if j < min(M_b, 5120) else 0.0
//   M_b = #bins with count >= 53; histogram over idx = rn(1000x)*1024 + rn(1000z)
//
// R1 global atomics: 646. R2/R3 region bucket-sort + LDS hist: 221.
// R4 FAILED fence-fusion (+90; per-block device-scope fences = XCD L2 storm;
//    rules out cooperative/grid-sync fusion too). R5/R6: 219.4 (fill 78 us).
// R7 occupancy/block-size: null. R8 parity cursors: null (+regr from masked hist).
// R9 DIAG x3: marginal warm full pass (loads+quantize+ALL atomics) ~21 us for
//    BOTH kernels -> atomics/conflicts are NOT the cost. R10 persistent: null.
// R11 vector flush + dense hist: null (218.0). Four structural nulls.
// => Arithmetic now pins the cost in the COLD first-pass read: B1 ~ 95 us for
//    134 MB = ~1.4-2.3 TB/s effective (R9 PMC), 4x below streaming peak,
//    despite ample MLP. Suspect: environmental throttle (512 MiB poison-fill
//    dirty-L3 eviction debt / latency pathology), untouchable by kernel shape.
// R12 (this): DECISIVE PROBE with upside. New K1 quantize_kernel: pure
//    streaming read 134 MB -> write 64 MiB u32 idx stream (no LDS/atomics,
//    max MLP). Bucketize reads the L3-warm idx stream (half the bytes);
//    rest is R11-exact. K1's counters answer "can ANY kernel here stream at
//    peak?". Healthy -> 185-205 total (keep). Pathological -> ~240, revert to
//    R11 next round and declare the environmental ceiling with evidence.

static constexpr int kB        = 64;
static constexpr int kN        = 262144;    // points per cloud
static constexpr int kTopK     = 5120;
static constexpr int kRegions  = 64;        // idx>>14 == xi>>4; xi<=1000 -> region<=62
static constexpr int kCap      = 6144;      // u16 slots per (cloud,region); mult of 8
static constexpr int kSlots    = 256;       // per-tile per-region LDS cap; mean ~128, +11 sigma
static constexpr int kStrideU16= 264;       // u16 stride per region chunk (528 B, 16B-aligned)
static constexpr int kThreads  = 256;
static constexpr int kPtsPerTile = 8192;    // 32 points/thread
static constexpr int kTilesPerCloud = kN / kPtsPerTile;          // 32
static constexpr int kBlocksA  = 1024;      // persistent bucketize blocks (4/CU)
static constexpr int kItersA   = kB * kTilesPerCloud / kBlocksA; // 2
static constexpr int kBlocksB  = 1024;      // persistent hist blocks
static constexpr int kItersB   = kB * kRegions / kBlocksB;       // 4
static constexpr int kBlocksQ  = 2048;      // quantize kernel blocks
static constexpr unsigned kThresh = 53;

// ws layout:
//   [0       ,16384  ) : gcnt_pad[4096]  u32
//   [16384   ,32768  ) : gcnt_true[4096] u32
//   [32768   ,33024  ) : occ[64]         u32
//   [65536   ,+64MiB ) : qidx  u32[16.7M] packed as uint2 (2 points each)
//   [67174400,+50.3MB) : bdata u16[4096][kCap]

__global__ void __launch_bounds__(kThreads) quantize_kernel(
    const float4* __restrict__ pcd4, uint2* __restrict__ qidx) {
    // Pure streaming: 8.4M float4 in, 8.4M uint2 out. 16 elems/thread.
    const int total = kB * kN / 2;                 // 8388608
    const int stride = kBlocksQ * kThreads;
    for (int i = (int)blockIdx.x * kThreads + threadIdx.x; i < total; i += stride) {
        float4 v = pcd4[i];
        // jnp.round == round-half-to-even -> __float2int_rn
        uint32_t i0 = (uint32_t)(__float2int_rn(1000.0f * v.x) * 1024 + __float2int_rn(1000.0f * v.y));
        uint32_t i1 = (uint32_t)(__float2int_rn(1000.0f * v.z) * 1024 + __float2int_rn(1000.0f * v.w));
        qidx[i] = make_uint2(i0, i1);
    }
}

__global__ void __launch_bounds__(kThreads) bucketize_kernel(
    const uint2* __restrict__ qidx, uint32_t* __restrict__ gcnt_pad,
    uint32_t* __restrict__ gcnt_true, uint16_t* __restrict__ bdata) {
    __shared__ uint4    s_stage4[kRegions * (kStrideU16 / 8)];  // 33792 B
    __shared__ uint32_t s_off[kRegions];
    __shared__ uint32_t s_gbase[kRegions];
    __shared__ uint32_t s_cl[kRegions];     // padded count per region (mult of 8)
    uint16_t* s_stage = (uint16_t*)s_stage4;

    const int tid = threadIdx.x;

    for (int it = 0; it < kItersA; ++it) {
        const int tile  = (int)blockIdx.x + it * kBlocksA;   // 0..2047
        const int cloud = tile >> 5;
        const int batch = tile & (kTilesPerCloud - 1);
        const size_t u2base =
            (size_t)cloud * (kN / 2) + (size_t)batch * (kPtsPerTile / 2);

        if (tid < kRegions) s_off[tid] = 0;
        __syncthreads();

        // idx-load -> split -> place into fixed-stride region chunk
        for (int c = 0; c < 4; ++c) {
            uint2 q[4];
#pragma unroll
            for (int j = 0; j < 4; ++j)
                q[j] = qidx[u2base + (size_t)(c * 4 + j) * kThreads + tid];
#pragma unroll
            for (int j = 0; j < 4; ++j) {
                uint32_t i0 = q[j].x, i1 = q[j].y;
                uint32_t r0 = i0 >> 14, b0 = i0 & 16383u;
                uint32_t r1 = i1 >> 14, b1 = i1 & 16383u;
                uint32_t p0 = atomicAdd(&s_off[r0], 1u);
                if (p0 < (uint32_t)kSlots) s_stage[r0 * kStrideU16 + p0] = (uint16_t)b0;
                uint32_t p1 = atomicAdd(&s_off[r1], 1u);
                if (p1 < (uint32_t)kSlots) s_stage[r1 * kStrideU16 + p1] = (uint16_t)b1;
            }
        }
        __syncthreads();

        if (tid < kRegions) {   // reserve padded range; pads = bin 0 of region
            uint32_t c = s_off[tid];
            if (c > (uint32_t)kSlots) c = (uint32_t)kSlots;
            uint32_t cp = (c + 7u) & ~7u;               // <= kSlots
            for (uint32_t k = c; k < cp; ++k) s_stage[tid * kStrideU16 + k] = 0;
            s_cl[tid] = cp;
            s_gbase[tid] = atomicAdd(&gcnt_pad[cloud * kRegions + tid], cp);
            atomicAdd(&gcnt_true[cloud * kRegions + tid], c);
        }
        __syncthreads();

        // Flush: all-vector ds_read_b128 + dense uint4 stores.
        for (int j = 0; j < kRegions * kSlots / 8 / kThreads; ++j) {  // 8
            int i = j * kThreads + tid;
            uint32_t r = (uint32_t)i >> 5;
            uint32_t o = ((uint32_t)i & 31u) << 3;       // u16 offset, mult of 8
            uint32_t gb = s_gbase[r];
            if (o < s_cl[r] && gb + o + 8u <= (uint32_t)kCap) {
                uint4 v = s_stage4[r * (kStrideU16 / 8) + (o >> 3)];
                *(uint4*)&bdata[(((size_t)cloud * kRegions + r) * kCap) + gb + o] = v;
            }
        }
        __syncthreads();   // s_stage/s_gbase reused next iteration
    }
}

__global__ void __launch_bounds__(kThreads) region_hist_kernel(
    const uint32_t* __restrict__ gcnt_pad, const uint32_t* __restrict__ gcnt_true,
    const uint16_t* __restrict__ bdata, uint32_t* __restrict__ occ) {
    // u16-packed counters: 16384 bins in 8192 u32 = 32 KB. Bin count bounded by
    // processed entries (<= kCap = 6144 < 65536): no overflow for ANY input.
    __shared__ uint32_t hist[8192];
    const int tid = threadIdx.x;
    uint4* h4 = (uint4*)hist;

    for (int it = 0; it < kItersB; ++it) {
        const int pair = (int)blockIdx.x + it * kBlocksB;  // cloud*64 + region

        for (int i = tid; i < 8192 / 4; i += kThreads) h4[i] = make_uint4(0, 0, 0, 0);
        __syncthreads();

        uint32_t cnt = gcnt_pad[pair];
        if (cnt > (uint32_t)kCap) cnt = (uint32_t)kCap;
        const uint4* src4 = (const uint4*)(bdata + (size_t)pair * kCap);
        const uint32_t groups = cnt >> 3;                  // DENSE, no tail
        for (uint32_t g = tid; g < groups; g += kThreads) {
            uint4 v = src4[g];
            uint32_t w;
            w = v.x; atomicAdd(&hist[(w & 0xFFFFu) >> 1], 1u << (16u * (w & 1u)));
                     w >>= 16; atomicAdd(&hist[w >> 1], 1u << (16u * (w & 1u)));
            w = v.y; atomicAdd(&hist[(w & 0xFFFFu) >> 1], 1u << (16u * (w & 1u)));
                     w >>= 16; atomicAdd(&hist[w >> 1], 1u << (16u * (w & 1u)));
            w = v.z; atomicAdd(&hist[(w & 0xFFFFu) >> 1], 1u << (16u * (w & 1u)));
                     w >>= 16; atomicAdd(&hist[w >> 1], 1u << (16u * (w & 1u)));
            w = v.w; atomicAdd(&hist[(w & 0xFFFFu) >> 1], 1u << (16u * (w & 1u)));
                     w >>= 16; atomicAdd(&hist[w >> 1], 1u << (16u * (w & 1u)));
        }
        __syncthreads();

        if (tid == 0) {   // remove pad entries (all were bin 0 -> hist[0] low16)
            uint32_t pad = gcnt_pad[pair] - gcnt_true[pair];
            uint32_t lo = hist[0] & 0xFFFFu;
            if (pad > lo) pad = lo;
            hist[0] -= pad;
        }
        __syncthreads();

        uint32_t local = 0;
        for (int i = tid; i < 8192 / 4; i += kThreads) {
            uint4 v = h4[i];
            local += ((v.x & 0xFFFFu) >= kThresh) + ((v.x >> 16) >= kThresh);
            local += ((v.y & 0xFFFFu) >= kThresh) + ((v.y >> 16) >= kThresh);
            local += ((v.z & 0xFFFFu) >= kThresh) + ((v.z >> 16) >= kThresh);
            local += ((v.w & 0xFFFFu) >= kThresh) + ((v.w >> 16) >= kThresh);
        }
#pragma unroll
        for (int d = 32; d; d >>= 1) local += __shfl_down(local, d, 64);
        if ((tid & 63) == 0 && local)
            atomicAdd(&occ[pair >> 6], local);  // <=4 global atomics per pair
        __syncthreads();   // hist reused next iteration
    }
}

__global__ void __launch_bounds__(kThreads) out_kernel(const uint32_t* __restrict__ occ,
                                                       float* __restrict__ out) {
    const int b = blockIdx.x;
    const uint32_t m = occ[b];
    const uint32_t cut = m < (uint32_t)kTopK ? m : (uint32_t)kTopK;
    float4* row = (float4*)(out + (size_t)b * kTopK);
    for (int i = threadIdx.x; i < kTopK / 4; i += kThreads) {
        uint32_t j = (uint32_t)i * 4u;
        row[i] = make_float4(j < cut ? 1.0f : 0.0f, j + 1 < cut ? 1.0f : 0.0f,
                             j + 2 < cut ? 1.0f : 0.0f, j + 3 < cut ? 1.0f : 0.0f);
    }
}

extern "C" void kernel_launch(void* const* d_in, const int* in_sizes, int n_in,
                              void* d_out, int out_size, void* d_ws, size_t ws_size,
                              hipStream_t stream) {
    const float4* pcd4 = (const float4*)d_in[0];
    float* out = (float*)d_out;

    uint32_t* gcnt_pad  = (uint32_t*)d_ws;                        // 16 KB
    uint32_t* gcnt_true = (uint32_t*)((char*)d_ws + 16384);       // 16 KB
    uint32_t* occ       = (uint32_t*)((char*)d_ws + 32768);       // 256 B
    uint2*    qidx      = (uint2*)((char*)d_ws + 65536);          // 64 MiB
    uint16_t* bdata     = (uint16_t*)((char*)d_ws + 67174400);    // 50.3 MB

    // Zero only the cursors/counters (ws re-poisoned to 0xAA each call).
    hipMemsetAsync(d_ws, 0, 33024, stream);

    // K1: pure streaming quantize probe (134 MB -> 64 MiB idx stream)
    quantize_kernel<<<kBlocksQ, kThreads, 0, stream>>>(pcd4, qidx);

    // persistent: 1024 blocks x 2 batch-tiles, reads idx stream
    bucketize_kernel<<<kBlocksA, kThreads, 0, stream>>>(qidx, gcnt_pad, gcnt_true, bdata);

    // persistent: 1024 blocks x 4 (cloud, region) pairs
    region_hist_kernel<<<kBlocksB, kThreads, 0, stream>>>(gcnt_pad, gcnt_true, bdata, occ);

    // one block per cloud
    out_kernel<<<kB, kThreads, 0, stream>>>(occ, out);
}

// Round 8
// 218.217 us; speedup vs baseline: 1.1228x; 1.1228x over previous
//
#include <hip/hip_runtime.h>
#include <stdint.h>

// occupancy_generation (DeepMapping2D):
//   out[b, j] = 1.0 if j < min(M_b, 5120) else 0.0
//   M_b = #bins with count >= 53; histogram over idx = rn(1000x)*1024 + rn(1000z)
//
// FINAL STRUCTURE (R11, 218.0 us verified). Optimization history:
// R1 global atomics: 646. R2/R3 region bucket-sort + LDS hist: 221.
// R4 FAILED fence-fusion (+90; device-scope fences = XCD L2 storm).
// R5/R6: split kernels, 219.4. R7 occupancy/block-size: null.
// R8 parity cursors: null (same-address serialization refuted).
// R9 DIAG x3: warm repeat of ALL per-point work (loads+quantize+33.5M LDS
//    atomics) = ~21 us -> compute/atomic pipes are NOT the bottleneck.
// R10 persistent 1024-blocks: null (launch ramp refuted).
// R11 padded segments: vector flush (ds_read_b128 + uint4 stores) + fully
//    dense hist groups. 218.0. Four structural levers all null.
// R12 DECISIVE PROBE: pure-streaming quantize pre-pass (no LDS/atomics, max
//    MLP) could NOT stream the input fast either; net +21-27 us = the extra
//    round-trip at throttled rates. CONCLUSION: remaining time is
//    environmental, not structural:
//      78 us  512MiB 0xAA re-poison fill (harness, inside timed iter)
//     ~95 us  cold first-touch input read throttled to ~1.5-2.4 TB/s by the
//             fill's dirty-L3 eviction debt (the fill itself writes at 6.9)
//     ~45 us  hist + out + memset + inter-kernel gaps
//    = ~218 us. Structure-controllable residual: single-digit us. ROOFLINE.

static constexpr int kB        = 64;
static constexpr int kN        = 262144;    // points per cloud
static constexpr int kTopK     = 5120;
static constexpr int kRegions  = 64;        // idx>>14 == xi>>4; xi<=1000 -> region<=62
static constexpr int kCap      = 6144;      // u16 slots per (cloud,region); mult of 8
static constexpr int kSlots    = 256;       // per-tile per-region LDS cap; mean ~128, +11 sigma
static constexpr int kStrideU16= 264;       // u16 stride per region chunk (528 B, 16B-aligned)
static constexpr int kThreads  = 256;
static constexpr int kPtsPerTile = 8192;    // 32 points/thread
static constexpr int kTilesPerCloud = kN / kPtsPerTile;          // 32
static constexpr int kBlocksA  = 1024;      // persistent bucketize blocks (4/CU)
static constexpr int kItersA   = kB * kTilesPerCloud / kBlocksA; // 2
static constexpr int kBlocksB  = 1024;      // persistent hist blocks
static constexpr int kItersB   = kB * kRegions / kBlocksB;       // 4
static constexpr unsigned kThresh = 53;

// ws layout:
//   [0     ,16384) : gcnt_pad[4096]  u32  (padded cursors; placement offsets)
//   [16384 ,32768) : gcnt_true[4096] u32  (true entry counts)
//   [32768 ,33024) : occ[64]         u32  (per-cloud occupied-bin counts)
//   [65536 , ... ) : bdata[4096][kCap] u16 (segments; 16B-aligned, 8-u16 padded)

__global__ void __launch_bounds__(kThreads) bucketize_kernel(
    const float4* __restrict__ pcd4, uint32_t* __restrict__ gcnt_pad,
    uint32_t* __restrict__ gcnt_true, uint16_t* __restrict__ bdata) {
    __shared__ uint4    s_stage4[kRegions * (kStrideU16 / 8)];  // 33792 B, 16B-aligned
    __shared__ uint32_t s_off[kRegions];
    __shared__ uint32_t s_gbase[kRegions];
    __shared__ uint32_t s_cl[kRegions];     // padded count per region (mult of 8)
    uint16_t* s_stage = (uint16_t*)s_stage4;

    const int tid = threadIdx.x;

    for (int it = 0; it < kItersA; ++it) {
        const int tile  = (int)blockIdx.x + it * kBlocksA;   // 0..2047
        const int cloud = tile >> 5;
        const int batch = tile & (kTilesPerCloud - 1);
        const size_t f4base =
            (size_t)cloud * (kN / 2) + (size_t)batch * (kPtsPerTile / 2);

        if (tid < kRegions) s_off[tid] = 0;
        __syncthreads();

        // load -> quantize -> place into fixed-stride region chunk
        for (int c = 0; c < 4; ++c) {
            float4 v[4];
#pragma unroll
            for (int j = 0; j < 4; ++j)
                v[j] = pcd4[f4base + (size_t)(c * 4 + j) * kThreads + tid];
#pragma unroll
            for (int j = 0; j < 4; ++j) {
                // jnp.round == round-half-to-even -> __float2int_rn
                int i0 = __float2int_rn(1000.0f * v[j].x) * 1024 + __float2int_rn(1000.0f * v[j].y);
                int i1 = __float2int_rn(1000.0f * v[j].z) * 1024 + __float2int_rn(1000.0f * v[j].w);
                uint32_t r0 = (uint32_t)i0 >> 14, b0 = (uint32_t)i0 & 16383u;
                uint32_t r1 = (uint32_t)i1 >> 14, b1 = (uint32_t)i1 & 16383u;
                uint32_t p0 = atomicAdd(&s_off[r0], 1u);
                if (p0 < (uint32_t)kSlots) s_stage[r0 * kStrideU16 + p0] = (uint16_t)b0;
                uint32_t p1 = atomicAdd(&s_off[r1], 1u);
                if (p1 < (uint32_t)kSlots) s_stage[r1 * kStrideU16 + p1] = (uint16_t)b1;
            }
        }
        __syncthreads();

        if (tid < kRegions) {   // reserve padded range; pads = bin 0 of region
            uint32_t c = s_off[tid];
            if (c > (uint32_t)kSlots) c = (uint32_t)kSlots;
            uint32_t cp = (c + 7u) & ~7u;               // <= kSlots (256 = 32*8)
            for (uint32_t k = c; k < cp; ++k) s_stage[tid * kStrideU16 + k] = 0;
            s_cl[tid] = cp;
            s_gbase[tid] = atomicAdd(&gcnt_pad[cloud * kRegions + tid], cp);
            atomicAdd(&gcnt_true[cloud * kRegions + tid], c);
        }
        __syncthreads();

        // Flush: 64 regions x 32 chunks of 16B = 2048 chunks / 256 thr = 8 iters.
        // All-vector: ds_read_b128 + uint4 global store, dense within padded count.
        for (int j = 0; j < kRegions * kSlots / 8 / kThreads; ++j) {  // 8
            int i = j * kThreads + tid;
            uint32_t r = (uint32_t)i >> 5;
            uint32_t o = ((uint32_t)i & 31u) << 3;       // u16 offset, mult of 8
            uint32_t gb = s_gbase[r];
            if (o < s_cl[r] && gb + o + 8u <= (uint32_t)kCap) {
                uint4 v = s_stage4[r * (kStrideU16 / 8) + (o >> 3)];
                *(uint4*)&bdata[(((size_t)cloud * kRegions + r) * kCap) + gb + o] = v;
            }
        }
        __syncthreads();   // s_stage/s_gbase reused next iteration
    }
}

__global__ void __launch_bounds__(kThreads) region_hist_kernel(
    const uint32_t* __restrict__ gcnt_pad, const uint32_t* __restrict__ gcnt_true,
    const uint16_t* __restrict__ bdata, uint32_t* __restrict__ occ) {
    // u16-packed counters: 16384 bins in 8192 u32 = 32 KB. A bin's count is
    // bounded by processed entries (<= kCap = 6144 < 65536): no overflow.
    __shared__ uint32_t hist[8192];
    const int tid = threadIdx.x;
    uint4* h4 = (uint4*)hist;

    for (int it = 0; it < kItersB; ++it) {
        const int pair = (int)blockIdx.x + it * kBlocksB;  // cloud*64 + region

        for (int i = tid; i < 8192 / 4; i += kThreads) h4[i] = make_uint4(0, 0, 0, 0);
        __syncthreads();

        uint32_t cnt = gcnt_pad[pair];
        if (cnt > (uint32_t)kCap) cnt = (uint32_t)kCap;   // kCap mult of 8
        const uint4* src4 = (const uint4*)(bdata + (size_t)pair * kCap);
        const uint32_t groups = cnt >> 3;                  // DENSE: no masking, no tail
        for (uint32_t g = tid; g < groups; g += kThreads) {
            uint4 v = src4[g];
            uint32_t w;
            w = v.x; atomicAdd(&hist[(w & 0xFFFFu) >> 1], 1u << (16u * (w & 1u)));
                     w >>= 16; atomicAdd(&hist[w >> 1], 1u << (16u * (w & 1u)));
            w = v.y; atomicAdd(&hist[(w & 0xFFFFu) >> 1], 1u << (16u * (w & 1u)));
                     w >>= 16; atomicAdd(&hist[w >> 1], 1u << (16u * (w & 1u)));
            w = v.z; atomicAdd(&hist[(w & 0xFFFFu) >> 1], 1u << (16u * (w & 1u)));
                     w >>= 16; atomicAdd(&hist[w >> 1], 1u << (16u * (w & 1u)));
            w = v.w; atomicAdd(&hist[(w & 0xFFFFu) >> 1], 1u << (16u * (w & 1u)));
                     w >>= 16; atomicAdd(&hist[w >> 1], 1u << (16u * (w & 1u)));
        }
        __syncthreads();

        if (tid == 0) {   // remove pad entries (all were bin 0 -> hist[0] low16)
            uint32_t pad = gcnt_pad[pair] - gcnt_true[pair];
            uint32_t lo = hist[0] & 0xFFFFu;
            if (pad > lo) pad = lo;    // only reachable in astronomically-rare cap overflow
            hist[0] -= pad;
        }
        __syncthreads();

        uint32_t local = 0;
        for (int i = tid; i < 8192 / 4; i += kThreads) {
            uint4 v = h4[i];
            local += ((v.x & 0xFFFFu) >= kThresh) + ((v.x >> 16) >= kThresh);
            local += ((v.y & 0xFFFFu) >= kThresh) + ((v.y >> 16) >= kThresh);
            local += ((v.z & 0xFFFFu) >= kThresh) + ((v.z >> 16) >= kThresh);
            local += ((v.w & 0xFFFFu) >= kThresh) + ((v.w >> 16) >= kThresh);
        }
#pragma unroll
        for (int d = 32; d; d >>= 1) local += __shfl_down(local, d, 64);
        if ((tid & 63) == 0 && local)
            atomicAdd(&occ[pair >> 6], local);  // <=4 global atomics per pair
        __syncthreads();   // hist reused next iteration
    }
}

__global__ void __launch_bounds__(kThreads) out_kernel(const uint32_t* __restrict__ occ,
                                                       float* __restrict__ out) {
    // 64 blocks; block b writes cloud b's 5120-float row with float4 stores.
    const int b = blockIdx.x;
    const uint32_t m = occ[b];
    const uint32_t cut = m < (uint32_t)kTopK ? m : (uint32_t)kTopK;
    float4* row = (float4*)(out + (size_t)b * kTopK);
    for (int i = threadIdx.x; i < kTopK / 4; i += kThreads) {
        uint32_t j = (uint32_t)i * 4u;
        row[i] = make_float4(j < cut ? 1.0f : 0.0f, j + 1 < cut ? 1.0f : 0.0f,
                             j + 2 < cut ? 1.0f : 0.0f, j + 3 < cut ? 1.0f : 0.0f);
    }
}

extern "C" void kernel_launch(void* const* d_in, const int* in_sizes, int n_in,
                              void* d_out, int out_size, void* d_ws, size_t ws_size,
                              hipStream_t stream) {
    const float4* pcd4 = (const float4*)d_in[0];
    float* out = (float*)d_out;

    uint32_t* gcnt_pad  = (uint32_t*)d_ws;                       // 16 KB
    uint32_t* gcnt_true = (uint32_t*)((char*)d_ws + 16384);      // 16 KB
    uint32_t* occ       = (uint32_t*)((char*)d_ws + 32768);      // 256 B
    uint16_t* bdata     = (uint16_t*)((char*)d_ws + 65536);      // 50.3 MB

    // Zero only the cursors/counters (ws re-poisoned to 0xAA each call).
    hipMemsetAsync(d_ws, 0, 33024, stream);

    // persistent: 1024 blocks x 2 batch-tiles
    bucketize_kernel<<<kBlocksA, kThreads, 0, stream>>>(pcd4, gcnt_pad, gcnt_true, bdata);

    // persistent: 1024 blocks x 4 (cloud, region) pairs
    region_hist_kernel<<<kBlocksB, kThreads, 0, stream>>>(gcnt_pad, gcnt_true, bdata, occ);

    // one block per cloud
    out_kernel<<<kB, kThreads, 0, stream>>>(occ, out);
}